// Round 17
// baseline (8200.668 us; speedup 1.0000x reference)
//
#include <hip/hip_runtime.h>
#include <math.h>

#define NN 2000
#define BB 32
#define TT 24
#define T_OUT 12
#define HH 64
#define DD 10
#define NP 2048   // padded node dim
#define BC 2048   // B*H columns (j = b*64 + c)

typedef unsigned short ushort_t;
typedef __bf16 bf16x8 __attribute__((ext_vector_type(8)));
typedef float f32x4 __attribute__((ext_vector_type(4)));

__device__ __forceinline__ float sigmoidf_(float x) { return 1.f / (1.f + expf(-x)); }

__device__ __forceinline__ ushort_t f2bf(float f) {
    unsigned int u = __float_as_uint(f);
    unsigned int r = (u + 0x7FFFu + ((u >> 16) & 1u)) >> 16;
    return (ushort_t)r;
}
__device__ __forceinline__ float bf2f(ushort_t s) {
    return __uint_as_float(((unsigned int)s) << 16);
}

__device__ __forceinline__ void glld16(const ushort_t* g, ushort_t* lds) {
    __builtin_amdgcn_global_load_lds(
        (const __attribute__((address_space(1))) char*)g,
        (__attribute__((address_space(3))) char*)lds, 16, 0, 0);
}

__device__ __forceinline__ unsigned lds_off(const void* p) {
    return (unsigned)(size_t)(__attribute__((address_space(3))) const char*)p;
}

// ---------------- workspace layout (bytes) ----------------
constexpr size_t SZ_NPNP2 = (size_t)NP * NP * 2;   // 8,388,608
constexpr size_t SZ_ST4   = (size_t)NN * BC * 4;   // 16,384,000
constexpr size_t SZ_NPB2  = (size_t)NP * BC * 2;   // 8,388,608 (padded bf16 state)

constexpr size_t ABF_OFF  = 0;
constexpr size_t H0F_OFF  = ABF_OFF + SZ_NPNP2;
constexpr size_t H1F_OFF  = H0F_OFF + SZ_ST4;
constexpr size_t ZF_OFF   = H1F_OFF + SZ_ST4;       // f32; overlaid with A_f32 in setup
constexpr size_t H0B_OFF  = ZF_OFF + SZ_ST4;
constexpr size_t H1B_OFF  = H0B_OFF + SZ_NPB2;
constexpr size_t RHB_OFF  = H1B_OFF + SZ_NPB2;
constexpr size_t AH0_OFF  = RHB_OFF + SZ_NPB2;
constexpr size_t AHX_OFF  = AH0_OFF + SZ_NPB2;
constexpr size_t AXF_OFF  = AHX_OFF + SZ_NPB2;      // [B][T][N] f32
constexpr size_t BTG0_OFF = AXF_OFF + (size_t)BB * TT * NN * 4;
constexpr size_t BTC0_OFF = BTG0_OFF + (size_t)DD * 128 * 128 * 2;  // 327,680
constexpr size_t BTG1_OFF = BTC0_OFF + (size_t)DD * 64 * 128 * 2;   // 163,840
constexpr size_t BTC1_OFF = BTG1_OFF + (size_t)DD * 128 * 256 * 2;  // 655,360
constexpr size_t WS_TOP   = BTC1_OFF + (size_t)DD * 64 * 256 * 2;   // 107,102,208
// pipelined-path extension (r12/r13)
constexpr size_t ZF1_OFF  = WS_TOP;                      // f32 16,384,000
constexpr size_t RHB1_OFF = ZF1_OFF + SZ_ST4;            // bf16 8,388,608
constexpr size_t AHY_OFF  = RHB1_OFF + SZ_NPB2;          // bf16 8,388,608
constexpr size_t TOP_PIPE = AHY_OFF + SZ_NPB2;           // 140,263,424
// pipe2 extension: parity copy of h0b
constexpr size_t H0B2_OFF = TOP_PIPE;                    // bf16 8,388,608
constexpr size_t TOP_PIPE2 = H0B2_OFF + SZ_NPB2;         // 148,652,032

// ---------------- A_f32 = row_softmax(relu(E E^T)) ----------------
__global__ __launch_bounds__(256) void compute_A_kernel(const float* __restrict__ E,
                                                        float* __restrict__ A) {
    const int row = blockIdx.x;
    const int tid = threadIdx.x;
    float er[DD];
#pragma unroll
    for (int d = 0; d < DD; ++d) er[d] = E[row * DD + d];
    __shared__ float red[8];

    float lmax = -1e30f;
    for (int c = tid; c < NN; c += 256) {
        float s = 0.f;
#pragma unroll
        for (int d = 0; d < DD; ++d) s += er[d] * E[c * DD + d];
        s = fmaxf(s, 0.f);
        A[(size_t)row * NN + c] = s;
        lmax = fmaxf(lmax, s);
    }
#pragma unroll
    for (int o = 32; o > 0; o >>= 1) lmax = fmaxf(lmax, __shfl_down(lmax, o, 64));
    if ((tid & 63) == 0) red[tid >> 6] = lmax;
    __syncthreads();
    const float rmax = fmaxf(fmaxf(red[0], red[1]), fmaxf(red[2], red[3]));
    __syncthreads();

    float lsum = 0.f;
    for (int c = tid; c < NN; c += 256) {
        float v = expf(A[(size_t)row * NN + c] - rmax);
        A[(size_t)row * NN + c] = v;
        lsum += v;
    }
#pragma unroll
    for (int o = 32; o > 0; o >>= 1) lsum += __shfl_down(lsum, o, 64);
    if ((tid & 63) == 0) red[4 + (tid >> 6)] = lsum;
    __syncthreads();
    const float inv = 1.f / (red[4] + red[5] + red[6] + red[7]);
    for (int c = tid; c < NN; c += 256) A[(size_t)row * NN + c] *= inv;
}

// ---------------- A_f32 -> A_bf [2048][2048] with zero pad ----------------
__global__ __launch_bounds__(256) void convert_A(const float* __restrict__ Af,
                                                 ushort_t* __restrict__ Ab) {
    size_t idx = (size_t)blockIdx.x * 256 + threadIdx.x;
    int r = (int)(idx >> 11), c = (int)(idx & 2047);
    float v = (r < NN && c < NN) ? Af[(size_t)r * NN + c] : 0.f;
    Ab[idx] = f2bf(v);
}

// ---------------- Ax[b,t,n] = sum_m A[n,m] x[b,t,m]  (f32, one-time) ----------------
// v6: v5 with odd LDS strides (67/27) -> 2-way write aliasing (free). Bit-identical Ax.
__global__ __launch_bounds__(256) void ax2_kernel(const float* __restrict__ A,
                                                  const float* __restrict__ x,
                                                  float* __restrict__ Ax) {
    __shared__ float As[64][67];  // [mm][r]
    __shared__ float xs[64][27];  // [mm][t], 24 used
    const int n0 = blockIdx.x * 64;
    const int b = blockIdx.y;
    const int tid = threadIdx.x;
    const int lane = tid & 63, cq = tid >> 6;  // cq = wave id, cols cq*6..cq*6+5
    float acc[6] = {};

    for (int m0 = 0; m0 < NN; m0 += 64) {
#pragma unroll
        for (int l = 0; l < 16; ++l) {
            int idx = tid + l * 256;
            int mm = idx & 63, r = idx >> 6;
            int n = n0 + r, m = m0 + mm;
            As[mm][r] = (n < NN && m < NN) ? A[(size_t)n * NN + m] : 0.f;
        }
#pragma unroll
        for (int l = 0; l < 6; ++l) {
            int idx = tid + l * 256;
            int mm = idx & 63, t = idx >> 6;
            int m = m0 + mm;
            xs[mm][t] = (m < NN) ? x[((size_t)b * TT + t) * NN + m] : 0.f;
        }
        __syncthreads();
#pragma unroll 4
        for (int mm = 0; mm < 64; ++mm) {
            const float a = As[mm][lane];
            const float x0 = xs[mm][cq * 6];
            const float x1 = xs[mm][cq * 6 + 1];
            const float x2 = xs[mm][cq * 6 + 2];
            const float x3 = xs[mm][cq * 6 + 3];
            const float x4 = xs[mm][cq * 6 + 4];
            const float x5 = xs[mm][cq * 6 + 5];
            acc[0] += a * x0;
            acc[1] += a * x1;
            acc[2] += a * x2;
            acc[3] += a * x3;
            acc[4] += a * x4;
            acc[5] += a * x5;
        }
        __syncthreads();
    }
    const int n = n0 + lane;
    if (n < NN) {
#pragma unroll
        for (int j = 0; j < 6; ++j) {
            const int t = cq * 6 + j;
            Ax[((size_t)b * TT + t) * NN + n] = acc[j];
        }
    }
}

// ================== device bodies ==================

// MFMA GEMM body: 128x128 tile, BK=64, 32 KB smem. NW = waves/block (4 or 8).
template <int NW>
__device__ __forceinline__ void gemm_body(int bx, int by,
                                          const ushort_t* __restrict__ Ab,
                                          const ushort_t* __restrict__ H,
                                          ushort_t* __restrict__ Y, char* smem) {
    constexpr int TH = NW * 64;
    constexpr int SPW = 8 / NW;  // j-subtiles per wave
    ushort_t* As = (ushort_t*)smem;             // 16 KB (128 rows x 64 k)
    ushort_t* Bs = (ushort_t*)(smem + 16384);   // 16 KB (two 8 KB halves)
    const int tid = threadIdx.x;
    const int w = tid >> 6, l = tid & 63, lr = l & 15, lg = l >> 4;
    const int n0 = bx * 128, j0 = by * 128;
    f32x4 acc[8][SPW] = {};

    const unsigned bs0 = lds_off(Bs);
    unsigned btr_b[SPW];
#pragma unroll
    for (int nt = 0; nt < SPW; ++nt)
        btr_b[nt] = bs0 + 2u * ((unsigned)(w * SPW + nt) * 512 + (unsigned)lg * 128 + (unsigned)lr);

    for (int ks = 0; ks < NP / 64; ++ks) {
        const int k0 = ks * 64;
#pragma unroll
        for (int p = 0; p < 1024 / TH; ++p) {  // A: 128x64, XOR-swizzled
            const int idx = p * TH + tid;
            const int row = idx >> 3, sl = idx & 7;
            glld16(Ab + (size_t)(n0 + row) * NP + k0 + ((sl ^ (row & 7)) << 3),
                   (ushort_t*)((char*)As + idx * 16));
        }
#pragma unroll
        for (int p = 0; p < 1024 / TH; ++p) {  // B: two 32-row halves, tr-read subtile order
            const int idx = p * TH + tid;
            const int g = idx >> 9, li = idx & 511;
            const int row = k0 + g * 32 + ((li >> 3) & 7) * 4 + ((li >> 1) & 3);
            const int col = j0 + (li >> 6) * 16 + (li & 1) * 8;
            glld16(H + (size_t)row * BC + col,
                   (ushort_t*)((char*)Bs + g * 8192 + li * 16));
        }
        __syncthreads();

        unsigned long long bq[2][SPW][2];  // [kk][nt][half]
        if constexpr (SPW == 2) {
            asm volatile(
                "ds_read_b64_tr_b16 %0, %8 offset:0\n\t"
                "ds_read_b64_tr_b16 %1, %8 offset:128\n\t"
                "ds_read_b64_tr_b16 %2, %9 offset:0\n\t"
                "ds_read_b64_tr_b16 %3, %9 offset:128\n\t"
                "ds_read_b64_tr_b16 %4, %8 offset:8192\n\t"
                "ds_read_b64_tr_b16 %5, %8 offset:8320\n\t"
                "ds_read_b64_tr_b16 %6, %9 offset:8192\n\t"
                "ds_read_b64_tr_b16 %7, %9 offset:8320"
                : "=v"(bq[0][0][0]), "=v"(bq[0][0][1]), "=v"(bq[0][1][0]), "=v"(bq[0][1][1]),
                  "=v"(bq[1][0][0]), "=v"(bq[1][0][1]), "=v"(bq[1][1][0]), "=v"(bq[1][1][1])
                : "v"(btr_b[0]), "v"(btr_b[1]));
        } else {
            asm volatile(
                "ds_read_b64_tr_b16 %0, %4 offset:0\n\t"
                "ds_read_b64_tr_b16 %1, %4 offset:128\n\t"
                "ds_read_b64_tr_b16 %2, %4 offset:8192\n\t"
                "ds_read_b64_tr_b16 %3, %4 offset:8320"
                : "=v"(bq[0][0][0]), "=v"(bq[0][0][1]), "=v"(bq[1][0][0]), "=v"(bq[1][0][1])
                : "v"(btr_b[0]));
        }
        asm volatile("s_waitcnt lgkmcnt(0)" ::: "memory");
        __builtin_amdgcn_sched_barrier(0);
        bf16x8 bv[2][SPW];
#pragma unroll
        for (int kk = 0; kk < 2; ++kk)
#pragma unroll
            for (int nt = 0; nt < SPW; ++nt) {
                union { unsigned long long q[2]; bf16x8 f; } u;
                u.q[0] = bq[kk][nt][0];
                u.q[1] = bq[kk][nt][1];
                bv[kk][nt] = u.f;
            }

#pragma unroll
        for (int kk = 0; kk < 2; ++kk)
#pragma unroll
            for (int m = 0; m < 8; ++m) {
                const int rr = m * 16 + lr;
                const bf16x8 av = *(const bf16x8*)&As[rr * 64 + (((kk * 4 + lg) ^ (rr & 7)) << 3)];
#pragma unroll
                for (int nt = 0; nt < SPW; ++nt)
                    acc[m][nt] = __builtin_amdgcn_mfma_f32_16x16x32_bf16(av, bv[kk][nt], acc[m][nt], 0, 0, 0);
            }
        __syncthreads();
    }

#pragma unroll
    for (int m = 0; m < 8; ++m)
#pragma unroll
        for (int r = 0; r < 4; ++r) {
            const int n = n0 + m * 16 + lg * 4 + r;
            if (n < NN) {
#pragma unroll
                for (int nt = 0; nt < SPW; ++nt)
                    Y[(size_t)n * BC + j0 + (w * SPW + nt) * 16 + lr] = f2bf(acc[m][nt][r]);
            }
        }
}

// factored-MFMA NAPL body (LDS-staged + av-hoist over d). smem = NSEGS*8 KB. 4 waves.
// d-loop unroll 2: doubles in-flight bv (L2) loads per wave; d-ascending OUT
// accumulation order preserved -> bit-identical.
template <int NSEGS, int CO, bool GATE, bool HASX>
__device__ __forceinline__ void napl_body(
    int bid, char* smem,
    const ushort_t* __restrict__ Bt, const float* __restrict__ bp,
    const float* __restrict__ emb, const float* __restrict__ WxPool,
    const ushort_t* __restrict__ s0p, const ushort_t* __restrict__ s1p,
    const ushort_t* __restrict__ s2p, const ushort_t* __restrict__ s3p,
    const float* __restrict__ xv, const float* __restrict__ axv,
    const float* hf, float* __restrict__ zf,
    ushort_t* __restrict__ outb, float* outf, int t) {
    constexpr int K = NSEGS * 64;
    constexpr int NT = (CO == 128) ? 2 : 1;
    constexpr int NHALF = NSEGS / 2;
    ushort_t* As = (ushort_t*)smem;
    const int tid = threadIdx.x;
    const int w = tid >> 6, l = tid & 63, lr = l & 15, lg = l >> 4;
    const int n0 = bid * 2;
    const int ob = w * (16 * NT);
    const ushort_t* segs[4] = {s0p, s1p, s2p, s3p};

#pragma unroll
    for (int s = 0; s < NSEGS; ++s) {
        const ushort_t* sp = segs[s];
#pragma unroll
        for (int p = 0; p < 2; ++p) {
            const int idx = p * 256 + tid;
            const int row = idx >> 3, c16 = idx & 7;
            glld16(sp + (size_t)(n0 + (row >> 5)) * BC + (row & 31) * 64 +
                       ((c16 ^ (row & 7)) << 3),
                   (ushort_t*)((char*)As + s * 8192 + idx * 16));
        }
    }
    __syncthreads();

    f32x4 OUT[4][NT] = {};
#pragma unroll 1
    for (int hf2 = 0; hf2 < NHALF; ++hf2) {
        bf16x8 av[4][4];  // [c][m], c = s_local*2 + h2
#pragma unroll
        for (int c = 0; c < 4; ++c) {
            const int s = hf2 * 2 + (c >> 1);
            const int kin = (c & 1) * 32 + lg * 8;
#pragma unroll
            for (int m = 0; m < 4; ++m) {
                const int rr = m * 16 + lr;
                av[c][m] = *(const bf16x8*)&As[s * 4096 + rr * 64 + (kin ^ ((rr & 7) << 3))];
            }
        }
#pragma unroll 2
        for (int d = 0; d < DD; ++d) {
            const ushort_t* btd = Bt + (size_t)d * CO * K;
            const float ea = emb[n0 * DD + d];
            const float eb = emb[(n0 + 1) * DD + d];
            f32x4 P[4][NT] = {};
#pragma unroll
            for (int c = 0; c < 4; ++c) {
                const int kg = (hf2 * 2 + (c >> 1)) * 64 + (c & 1) * 32 + lg * 8;
                bf16x8 bv[NT];
#pragma unroll
                for (int nt = 0; nt < NT; ++nt)
                    bv[nt] = *(const bf16x8*)&btd[(size_t)(ob + nt * 16 + lr) * K + kg];
#pragma unroll
                for (int m = 0; m < 4; ++m)
#pragma unroll
                    for (int nt = 0; nt < NT; ++nt)
                        P[m][nt] = __builtin_amdgcn_mfma_f32_16x16x32_bf16(av[c][m], bv[nt], P[m][nt], 0, 0, 0);
            }
#pragma unroll
            for (int m = 0; m < 4; ++m) {
                const float e = (m < 2) ? ea : eb;
#pragma unroll
                for (int nt = 0; nt < NT; ++nt)
#pragma unroll
                    for (int r = 0; r < 4; ++r)
                        OUT[m][nt][r] += e * P[m][nt][r];
            }
        }
    }

    float bias[2][NT];
#pragma unroll
    for (int nd = 0; nd < 2; ++nd)
#pragma unroll
        for (int nt = 0; nt < NT; ++nt) {
            float s_ = 0.f;
#pragma unroll
            for (int d = 0; d < DD; ++d)
                s_ += emb[(n0 + nd) * DD + d] * bp[d * CO + ob + nt * 16 + lr];
            bias[nd][nt] = s_;
        }
    float wx[2][2][NT] = {};
    if (HASX) {
#pragma unroll
        for (int kk = 0; kk < 2; ++kk)
#pragma unroll
            for (int nd = 0; nd < 2; ++nd)
#pragma unroll
                for (int nt = 0; nt < NT; ++nt) {
                    float s_ = 0.f;
#pragma unroll
                    for (int d = 0; d < DD; ++d)
                        s_ += emb[(n0 + nd) * DD + d] *
                              WxPool[(size_t)(d * 2 + kk) * 65 * CO + ob + nt * 16 + lr];
                    wx[kk][nd][nt] = s_;
                }
    }

#pragma unroll
    for (int m = 0; m < 4; ++m) {
        const int nd = m >> 1;
        const int n = n0 + nd;
#pragma unroll
        for (int r = 0; r < 4; ++r) {
            const int row = m * 16 + lg * 4 + r;
            const int b = row & 31;
            const size_t nb = (size_t)n * BC + b * 64;
            float xt = 0.f, axt = 0.f;
            if (HASX) {
                xt = xv[((size_t)b * TT + t) * NN + n];
                axt = axv[((size_t)b * TT + t) * NN + n];
            }
#pragma unroll
            for (int nt = 0; nt < NT; ++nt) {
                const int o = ob + nt * 16 + lr;
                float val = OUT[m][nt][r] + bias[nd][nt];
                if (HASX) val += xt * wx[0][nd][nt] + axt * wx[1][nd][nt];
                if (GATE) {
                    const float sg = sigmoidf_(val);
                    if (ob < 64) {
                        zf[nb + o] = sg;
                    } else {
                        outb[nb + (o - 64)] = f2bf(sg * hf[nb + (o - 64)]);
                    }
                } else {
                    const float hc = tanhf(val);
                    const float z = zf[nb + o];
                    const float hn = z * hf[nb + o] + (1.f - z) * hc;
                    outf[nb + o] = hn;
                    outb[nb + o] = f2bf(hn);
                }
            }
        }
    }
}

// ================== kernels ==================

__global__ __launch_bounds__(512) void gemm_trb(const ushort_t* __restrict__ Ab,
                                                const ushort_t* __restrict__ H0,
                                                ushort_t* __restrict__ Y0,
                                                const ushort_t* __restrict__ H1,
                                                ushort_t* __restrict__ Y1) {
    __shared__ __align__(16) char smem[32768];
    gemm_body<8>(blockIdx.x, blockIdx.y, Ab,
                 (blockIdx.z == 0) ? H0 : H1, (blockIdx.z == 0) ? Y0 : Y1, smem);
}

template <int NSEGS, int CO, bool GATE, bool HASX>
__global__ __launch_bounds__(256) void napl2(
    const ushort_t* __restrict__ Bt, const float* __restrict__ bp,
    const float* __restrict__ emb, const float* __restrict__ WxPool,
    const ushort_t* __restrict__ s0p, const ushort_t* __restrict__ s1p,
    const ushort_t* __restrict__ s2p, const ushort_t* __restrict__ s3p,
    const float* __restrict__ xv, const float* __restrict__ axv,
    const float* hf, float* __restrict__ zf,
    ushort_t* __restrict__ outb, float* outf, int t) {
    __shared__ __align__(16) char smem[NSEGS * 8192];
    napl_body<NSEGS, CO, GATE, HASX>(blockIdx.x, smem, Bt, bp, emb, WxPool,
                                     s0p, s1p, s2p, s3p, xv, axv, hf, zf, outb, outf, t);
}

// ---- r13-path merged kernels (4-wave gemm body; fallback only) ----
__global__ __launch_bounds__(256) void mergeA_k(
    const ushort_t* __restrict__ Abf, const ushort_t* __restrict__ Hg,
    ushort_t* __restrict__ Yg,
    const ushort_t* __restrict__ Bt, const float* __restrict__ bp,
    const float* __restrict__ emb, const float* __restrict__ Wx,
    const ushort_t* __restrict__ s0, const ushort_t* __restrict__ s1,
    const float* __restrict__ xv, const float* __restrict__ axv,
    const float* hf, float* __restrict__ zf, ushort_t* __restrict__ outb, int t) {
    __shared__ __align__(16) char smem[32768];
    const int g = blockIdx.x;
    if (g < 256)
        gemm_body<4>(g & 15, g >> 4, Abf, Hg, Yg, smem);
    else
        napl_body<2, 128, true, true>(g - 256, smem, Bt, bp, emb, Wx,
                                      s0, s1, s0, s0, xv, axv, hf, zf, outb, nullptr, t);
}

__global__ __launch_bounds__(256) void mergeB_k(
    const ushort_t* __restrict__ Abf, const ushort_t* __restrict__ Hg,
    ushort_t* __restrict__ Yg,
    const ushort_t* __restrict__ Bt, const float* __restrict__ bp,
    const float* __restrict__ emb,
    const ushort_t* __restrict__ s0, const ushort_t* __restrict__ s1,
    const ushort_t* __restrict__ s2, const ushort_t* __restrict__ s3,
    const float* hf, float* __restrict__ zf,
    ushort_t* __restrict__ outb, float* outf, int t) {
    __shared__ __align__(16) char smem[32768];
    const int g = blockIdx.x;
    if (g < 256)
        gemm_body<4>(g & 15, g >> 4, Abf, Hg, Yg, smem);
    else
        napl_body<4, 64, false, false>(g - 256, smem, Bt, bp, emb, nullptr,
                                       s0, s1, s2, s3, nullptr, nullptr, hf, zf, outb, outf, t);
}

__global__ __launch_bounds__(256) void mergeC_k(
    const ushort_t* __restrict__ Abf, const ushort_t* __restrict__ Hg,
    ushort_t* __restrict__ Yg,
    const ushort_t* __restrict__ Bt, const float* __restrict__ bp,
    const float* __restrict__ emb, const float* __restrict__ Wx,
    const ushort_t* __restrict__ s0, const ushort_t* __restrict__ s1,
    const float* __restrict__ xv, const float* __restrict__ axv,
    const float* hf, float* __restrict__ zf,
    ushort_t* __restrict__ outb, float* outf, int t) {
    __shared__ __align__(16) char smem[32768];
    const int g = blockIdx.x;
    if (g < 256)
        gemm_body<4>(g & 15, g >> 4, Abf, Hg, Yg, smem);
    else
        napl_body<2, 64, false, true>(g - 256, smem, Bt, bp, emb, Wx,
                                      s0, s1, s0, s0, xv, axv, hf, zf, outb, outf, t);
}

// ---- pipe2 merged kernels ----
// mergeG: blocks [0,1000) = layer1 GATE (t); [1000,2000) = layer0 GATE (t+1)
__global__ __launch_bounds__(256) void mergeG_k(
    const ushort_t* __restrict__ Btg1, const float* __restrict__ bg1,
    const ushort_t* __restrict__ Btg0, const float* __restrict__ bg0,
    const float* __restrict__ emb, const float* __restrict__ Wg0,
    const ushort_t* __restrict__ hbt, const ushort_t* __restrict__ Ah0,
    const ushort_t* __restrict__ h1b, const ushort_t* __restrict__ AhX,
    const float* __restrict__ xv, const float* __restrict__ axv,
    const float* h0f, const float* h1f,
    float* __restrict__ zf0, float* __restrict__ zf1,
    ushort_t* __restrict__ rhb0, ushort_t* __restrict__ rhb1, int t) {
    __shared__ __align__(16) char smem[32768];
    const int g = blockIdx.x;
    if (g < 1000)
        napl_body<4, 128, true, false>(g, smem, Btg1, bg1, emb, nullptr,
                                       hbt, Ah0, h1b, AhX, nullptr, nullptr,
                                       h1f, zf1, rhb1, nullptr, t);
    else
        napl_body<2, 128, true, true>(g - 1000, smem, Btg0, bg0, emb, Wg0,
                                      hbt, Ah0, hbt, hbt, xv, axv,
                                      h0f, zf0, rhb0, nullptr, t + 1);
}

// mergeCC: blocks [0,1000) = layer1 CAND (t); [1000,2000) = layer0 CAND (t+1)
__global__ __launch_bounds__(256) void mergeCC_k(
    const ushort_t* __restrict__ Btc1, const float* __restrict__ bc1,
    const ushort_t* __restrict__ Btc0, const float* __restrict__ bc0,
    const float* __restrict__ emb, const float* __restrict__ Wc0,
    const ushort_t* __restrict__ hbt, ushort_t* __restrict__ hbt1,
    const ushort_t* __restrict__ Ah0, const ushort_t* __restrict__ rhb1,
    const ushort_t* __restrict__ AhX, const ushort_t* __restrict__ AhY,
    const ushort_t* __restrict__ rhb0,
    const float* __restrict__ xv, const float* __restrict__ axv,
    float* h0f, float* h1f,
    float* __restrict__ zf0, float* __restrict__ zf1,
    ushort_t* __restrict__ h1b, int t) {
    __shared__ __align__(16) char smem[32768];
    const int g = blockIdx.x;
    if (g < 1000)
        napl_body<4, 64, false, false>(g, smem, Btc1, bc1, emb, nullptr,
                                       hbt, Ah0, rhb1, AhX, nullptr, nullptr,
                                       h1f, zf1, h1b, h1f, t);
    else
        napl_body<2, 64, false, true>(g - 1000, smem, Btc0, bc0, emb, Wc0,
                                      rhb0, AhY, rhb0, rhb0, xv, axv,
                                      h0f, zf0, hbt1, h0f, t + 1);
}

// ---------------- prep: Bt[d][o][K] bf16 from pool (B^T form for MFMA) ----------------
template <int CI, int CO, bool L0>
__global__ __launch_bounds__(256) void prepW(const float* __restrict__ Wp,
                                             ushort_t* __restrict__ Bt) {
    constexpr int K = L0 ? 128 : 256;
    const int idx = blockIdx.x * 256 + threadIdx.x;
    if (idx >= DD * CO * K) return;
    const int d = idx / (CO * K);
    const int rem = idx - d * CO * K;
    const int o = rem / K;
    const int k = rem - o * K;
    const int s = k >> 6, c = k & 63;
    const int kk = L0 ? s : (s & 1);
    const int i = L0 ? (1 + c) : ((s >> 1) * 64 + c);
    Bt[idx] = f2bf(Wp[((size_t)(d * 2 + kk) * CI + i) * CO + o]);
}

// ---------------- head ----------------
__global__ __launch_bounds__(256) void head_kernel(const float* __restrict__ h1,
                                                   const float* __restrict__ hw,
                                                   const float* __restrict__ hb,
                                                   float* __restrict__ y) {
    __shared__ float wl[T_OUT * HH];
    const int tid = threadIdx.x;
    for (int idx = tid; idx < T_OUT * HH; idx += 256) wl[idx] = hw[idx];
    __syncthreads();
    const int gi = blockIdx.x * 256 + tid;
    if (gi >= BB * NN) return;
    const int b = gi / NN, n = gi % NN;
    float acc[T_OUT];
#pragma unroll
    for (int ot = 0; ot < T_OUT; ++ot) acc[ot] = hb[ot];
    for (int h = 0; h < HH; ++h) {
        float v = h1[(size_t)n * BC + b * 64 + h];
#pragma unroll
        for (int ot = 0; ot < T_OUT; ++ot) acc[ot] += v * wl[ot * HH + h];
    }
#pragma unroll
    for (int ot = 0; ot < T_OUT; ++ot)
        y[((size_t)b * T_OUT + ot) * NN + n] = acc[ot];
}

extern "C" void kernel_launch(void* const* d_in, const int* in_sizes, int n_in,
                              void* d_out, int out_size, void* d_ws, size_t ws_size,
                              hipStream_t stream) {
    const float* x = (const float*)d_in[0];
    const float* node_emb = (const float*)d_in[1];
    const float* adapt_emb = (const float*)d_in[2];
    const float* Wg0 = (const float*)d_in[3];
    const float* bg0 = (const float*)d_in[4];
    const float* Wc0 = (const float*)d_in[5];
    const float* bc0 = (const float*)d_in[6];
    const float* Wg1 = (const float*)d_in[7];
    const float* bg1 = (const float*)d_in[8];
    const float* Wc1 = (const float*)d_in[9];
    const float* bc1 = (const float*)d_in[10];
    const float* head_w = (const float*)d_in[11];
    const float* head_b = (const float*)d_in[12];
    float* y = (float*)d_out;

    char* ws = (char*)d_ws;
    ushort_t* Abf  = (ushort_t*)(ws + ABF_OFF);
    float* h0f = (float*)(ws + H0F_OFF);
    float* h1f = (float*)(ws + H1F_OFF);
    float* zf  = (float*)(ws + ZF_OFF);
    ushort_t* h0b = (ushort_t*)(ws + H0B_OFF);
    ushort_t* h1b = (ushort_t*)(ws + H1B_OFF);
    ushort_t* rhb = (ushort_t*)(ws + RHB_OFF);
    ushort_t* Ah0 = (ushort_t*)(ws + AH0_OFF);
    ushort_t* AhX = (ushort_t*)(ws + AHX_OFF);
    float* Axf = (float*)(ws + AXF_OFF);
    ushort_t* Btg0 = (ushort_t*)(ws + BTG0_OFF);
    ushort_t* Btc0 = (ushort_t*)(ws + BTC0_OFF);
    ushort_t* Btg1 = (ushort_t*)(ws + BTG1_OFF);
    ushort_t* Btc1 = (ushort_t*)(ws + BTC1_OFF);
    float* Af32 = zf;  // overlay: consumed before first gate writes z

    const bool pipe2 = (ws_size >= TOP_PIPE2);
    const bool pipe = (ws_size >= TOP_PIPE);

    hipMemsetAsync(h0f, 0, SZ_ST4, stream);
    hipMemsetAsync(h1f, 0, SZ_ST4, stream);
    hipMemsetAsync(h0b, 0, SZ_NPB2, stream);
    hipMemsetAsync(h1b, 0, SZ_NPB2, stream);
    hipMemsetAsync(rhb, 0, SZ_NPB2, stream);
    hipMemsetAsync(Ah0, 0, SZ_NPB2, stream);
    hipMemsetAsync(AhX, 0, SZ_NPB2, stream);

    compute_A_kernel<<<NN, 256, 0, stream>>>(adapt_emb, Af32);
    ax2_kernel<<<dim3(32, 32), 256, 0, stream>>>(Af32, x, Axf);
    convert_A<<<(NP * NP) / 256, 256, 0, stream>>>(Af32, Abf);
    prepW<65, 128, true><<<(DD * 128 * 128 + 255) / 256, 256, 0, stream>>>(Wg0, Btg0);
    prepW<65, 64, true><<<(DD * 64 * 128 + 255) / 256, 256, 0, stream>>>(Wc0, Btc0);
    prepW<128, 128, false><<<(DD * 128 * 256 + 255) / 256, 256, 0, stream>>>(Wg1, Btg1);
    prepW<128, 64, false><<<(DD * 64 * 256 + 255) / 256, 256, 0, stream>>>(Wc1, Btc1);

    const dim3 gG1(NP / 128, NP / 128, 1);  // 256 blocks
    const dim3 gG2(NP / 128, NP / 128, 2);  // dual GEMM: 512 blocks
    const int gN = NN * BB / 64;            // 1000 blocks

    if (pipe2) {
        float* zf0 = zf;
        ushort_t* rhb0 = rhb;
        float* zf1 = (float*)(ws + ZF1_OFF);
        ushort_t* rhb1 = (ushort_t*)(ws + RHB1_OFF);
        ushort_t* AhY = (ushort_t*)(ws + AHY_OFF);
        ushort_t* h0b2 = (ushort_t*)(ws + H0B2_OFF);
        hipMemsetAsync(rhb1, 0, SZ_NPB2, stream);
        hipMemsetAsync(h0b2, 0, SZ_NPB2, stream);
        ushort_t* hb[2] = {h0b, h0b2};  // C0(t) writes hb[t&1]

        // prologue: G0(0), R0(0), C0(0) -> hb[0], G2(0) -> Ah0
        napl2<2, 128, true, true><<<gN, 256, 0, stream>>>(
            Btg0, bg0, node_emb, Wg0, h0b, Ah0, h0b, h0b, x, Axf, h0f, zf0, rhb0, nullptr, 0);
        gemm_trb<<<gG1, 512, 0, stream>>>(Abf, rhb0, AhY, rhb0, AhY);
        napl2<2, 64, false, true><<<gN, 256, 0, stream>>>(
            Btc0, bc0, node_emb, Wc0, rhb0, AhY, rhb0, rhb0, x, Axf, h0f, zf0, hb[0], h0f, 0);
        gemm_trb<<<gG1, 512, 0, stream>>>(Abf, hb[0], Ah0, hb[0], Ah0);

        for (int t = 0; t < TT - 1; ++t) {
            ushort_t* hbt = hb[t & 1];
            ushort_t* hbt1 = hb[(t + 1) & 1];
            // D1: G1(t) || G0(t+1)
            mergeG_k<<<2000, 256, 0, stream>>>(Btg1, bg1, Btg0, bg0, node_emb, Wg0,
                hbt, Ah0, h1b, AhX, x, Axf, h0f, h1f, zf0, zf1, rhb0, rhb1, t);
            // D2: R1(t): AhX <- A@rhb1 || R0(t+1): AhY <- A@rhb0
            gemm_trb<<<gG2, 512, 0, stream>>>(Abf, rhb1, AhX, rhb0, AhY);
            // D3: C1(t) -> h1f,h1b || C0(t+1) -> h0f,hbt1
            mergeCC_k<<<2000, 256, 0, stream>>>(Btc1, bc1, Btc0, bc0, node_emb, Wc0,
                hbt, hbt1, Ah0, rhb1, AhX, AhY, rhb0, x, Axf, h0f, h1f, zf0, zf1, h1b, t);
            // D4: AhX <- A@h1b || Ah0 <- A@hbt1
            gemm_trb<<<gG2, 512, 0, stream>>>(Abf, h1b, AhX, hbt1, Ah0);
        }
        // epilogue t=TT-1
        {
            ushort_t* hbT = hb[(TT - 1) & 1];
            napl2<4, 128, true, false><<<gN, 256, 0, stream>>>(
                Btg1, bg1, node_emb, nullptr, hbT, Ah0, h1b, AhX, nullptr, nullptr, h1f, zf1, rhb1, nullptr, TT - 1);
            gemm_trb<<<gG1, 512, 0, stream>>>(Abf, rhb1, AhX, rhb1, AhX);
            napl2<4, 64, false, false><<<gN, 256, 0, stream>>>(
                Btc1, bc1, node_emb, nullptr, hbT, Ah0, rhb1, AhX, nullptr, nullptr, h1f, zf1, h1b, h1f, TT - 1);
        }
    } else if (pipe) {
        float* zf0 = zf;
        ushort_t* rhb0 = rhb;
        float* zf1 = (float*)(ws + ZF1_OFF);
        ushort_t* rhb1 = (ushort_t*)(ws + RHB1_OFF);
        ushort_t* AhY = (ushort_t*)(ws + AHY_OFF);
        hipMemsetAsync(rhb1, 0, SZ_NPB2, stream);

        napl2<2, 128, true, true><<<gN, 256, 0, stream>>>(
            Btg0, bg0, node_emb, Wg0, h0b, Ah0, h0b, h0b, x, Axf, h0f, zf0, rhb0, nullptr, 0);
        gemm_trb<<<gG1, 512, 0, stream>>>(Abf, rhb0, AhY, rhb0, AhY);
        napl2<2, 64, false, true><<<gN, 256, 0, stream>>>(
            Btc0, bc0, node_emb, Wc0, rhb0, AhY, rhb0, rhb0, x, Axf, h0f, zf0, h0b, h0f, 0);
        gemm_trb<<<gG2, 512, 0, stream>>>(Abf, h0b, Ah0, h1b, AhX);
        napl2<4, 128, true, false><<<gN, 256, 0, stream>>>(
            Btg1, bg1, node_emb, nullptr, h0b, Ah0, h1b, AhX, nullptr, nullptr, h1f, zf1, rhb1, nullptr, 0);

        for (int t = 0; t < TT - 1; ++t) {
            mergeA_k<<<1256, 256, 0, stream>>>(Abf, rhb1, AhX,
                Btg0, bg0, node_emb, Wg0, h0b, Ah0, x, Axf, h0f, zf0, rhb0, t + 1);
            mergeB_k<<<1256, 256, 0, stream>>>(Abf, rhb0, AhY,
                Btc1, bc1, node_emb, h0b, Ah0, rhb1, AhX, h1f, zf1, h1b, h1f, t);
            mergeC_k<<<1256, 256, 0, stream>>>(Abf, h1b, AhX,
                Btc0, bc0, node_emb, Wc0, rhb0, AhY, x, Axf, h0f, zf0, h0b, h0f, t + 1);
            gemm_trb<<<gG1, 512, 0, stream>>>(Abf, h0b, Ah0, h0b, Ah0);
            napl2<4, 128, true, false><<<gN, 256, 0, stream>>>(
                Btg1, bg1, node_emb, nullptr, h0b, Ah0, h1b, AhX, nullptr, nullptr, h1f, zf1, rhb1, nullptr, t + 1);
        }
        gemm_trb<<<gG1, 512, 0, stream>>>(Abf, rhb1, AhX, rhb1, AhX);
        napl2<4, 64, false, false><<<gN, 256, 0, stream>>>(
            Btc1, bc1, node_emb, nullptr, h0b, Ah0, rhb1, AhX, nullptr, nullptr, h1f, zf1, h1b, h1f, TT - 1);
    } else {
        for (int t = 0; t < TT; ++t) {
            napl2<2, 128, true, true><<<gN, 256, 0, stream>>>(
                Btg0, bg0, node_emb, Wg0, h0b, Ah0, h0b, h0b, x, Axf, h0f, zf, rhb, nullptr, t);
            gemm_trb<<<gG1, 512, 0, stream>>>(Abf, rhb, AhX, rhb, AhX);
            napl2<2, 64, false, true><<<gN, 256, 0, stream>>>(
                Btc0, bc0, node_emb, Wc0, rhb, AhX, rhb, rhb, x, Axf, h0f, zf, h0b, h0f, t);
            gemm_trb<<<gG2, 512, 0, stream>>>(Abf, h0b, Ah0, h1b, AhX);
            napl2<4, 128, true, false><<<gN, 256, 0, stream>>>(
                Btg1, bg1, node_emb, nullptr, h0b, Ah0, h1b, AhX, nullptr, nullptr, h1f, zf, rhb, nullptr, t);
            gemm_trb<<<gG1, 512, 0, stream>>>(Abf, rhb, AhX, rhb, AhX);
            napl2<4, 64, false, false><<<gN, 256, 0, stream>>>(
                Btc1, bc1, node_emb, nullptr, h0b, Ah0, rhb, AhX, nullptr, nullptr, h1f, zf, h1b, h1f, t);
        }
    }

    head_kernel<<<(BB * NN + 255) / 256, 256, 0, stream>>>(h1f, head_w, head_b, y);
}

// Round 18
// 8108.776 us; speedup vs baseline: 1.0113x; 1.0113x over previous
//
#include <hip/hip_runtime.h>
#include <math.h>

#define NN 2000
#define BB 32
#define TT 24
#define T_OUT 12
#define HH 64
#define DD 10
#define NP 2048   // padded node dim
#define BC 2048   // B*H columns (j = b*64 + c)

typedef unsigned short ushort_t;
typedef __bf16 bf16x8 __attribute__((ext_vector_type(8)));
typedef float f32x4 __attribute__((ext_vector_type(4)));

__device__ __forceinline__ float sigmoidf_(float x) { return 1.f / (1.f + expf(-x)); }

__device__ __forceinline__ ushort_t f2bf(float f) {
    unsigned int u = __float_as_uint(f);
    unsigned int r = (u + 0x7FFFu + ((u >> 16) & 1u)) >> 16;
    return (ushort_t)r;
}
__device__ __forceinline__ float bf2f(ushort_t s) {
    return __uint_as_float(((unsigned int)s) << 16);
}

__device__ __forceinline__ void glld16(const ushort_t* g, ushort_t* lds) {
    __builtin_amdgcn_global_load_lds(
        (const __attribute__((address_space(1))) char*)g,
        (__attribute__((address_space(3))) char*)lds, 16, 0, 0);
}

__device__ __forceinline__ unsigned lds_off(const void* p) {
    return (unsigned)(size_t)(__attribute__((address_space(3))) const char*)p;
}

// ---------------- workspace layout (bytes) ----------------
constexpr size_t SZ_NPNP2 = (size_t)NP * NP * 2;   // 8,388,608
constexpr size_t SZ_ST4   = (size_t)NN * BC * 4;   // 16,384,000
constexpr size_t SZ_NPB2  = (size_t)NP * BC * 2;   // 8,388,608 (padded bf16 state)

constexpr size_t ABF_OFF  = 0;
constexpr size_t H0F_OFF  = ABF_OFF + SZ_NPNP2;
constexpr size_t H1F_OFF  = H0F_OFF + SZ_ST4;
constexpr size_t ZF_OFF   = H1F_OFF + SZ_ST4;       // f32; overlaid with A_f32 in setup
constexpr size_t H0B_OFF  = ZF_OFF + SZ_ST4;
constexpr size_t H1B_OFF  = H0B_OFF + SZ_NPB2;
constexpr size_t RHB_OFF  = H1B_OFF + SZ_NPB2;
constexpr size_t AH0_OFF  = RHB_OFF + SZ_NPB2;
constexpr size_t AHX_OFF  = AH0_OFF + SZ_NPB2;
constexpr size_t AXF_OFF  = AHX_OFF + SZ_NPB2;      // [B][T][N] f32
constexpr size_t BTG0_OFF = AXF_OFF + (size_t)BB * TT * NN * 4;
constexpr size_t BTC0_OFF = BTG0_OFF + (size_t)DD * 128 * 128 * 2;  // 327,680
constexpr size_t BTG1_OFF = BTC0_OFF + (size_t)DD * 64 * 128 * 2;   // 163,840
constexpr size_t BTC1_OFF = BTG1_OFF + (size_t)DD * 128 * 256 * 2;  // 655,360
constexpr size_t WS_TOP   = BTC1_OFF + (size_t)DD * 64 * 256 * 2;   // 107,102,208
// pipelined-path extension (r12/r13)
constexpr size_t ZF1_OFF  = WS_TOP;                      // f32 16,384,000
constexpr size_t RHB1_OFF = ZF1_OFF + SZ_ST4;            // bf16 8,388,608
constexpr size_t AHY_OFF  = RHB1_OFF + SZ_NPB2;          // bf16 8,388,608
constexpr size_t TOP_PIPE = AHY_OFF + SZ_NPB2;           // 140,263,424
// pipe2 extension: parity copy of h0b
constexpr size_t H0B2_OFF = TOP_PIPE;                    // bf16 8,388,608
constexpr size_t TOP_PIPE2 = H0B2_OFF + SZ_NPB2;         // 148,652,032

// ---------------- A_f32 = row_softmax(relu(E E^T)) ----------------
__global__ __launch_bounds__(256) void compute_A_kernel(const float* __restrict__ E,
                                                        float* __restrict__ A) {
    const int row = blockIdx.x;
    const int tid = threadIdx.x;
    float er[DD];
#pragma unroll
    for (int d = 0; d < DD; ++d) er[d] = E[row * DD + d];
    __shared__ float red[8];

    float lmax = -1e30f;
    for (int c = tid; c < NN; c += 256) {
        float s = 0.f;
#pragma unroll
        for (int d = 0; d < DD; ++d) s += er[d] * E[c * DD + d];
        s = fmaxf(s, 0.f);
        A[(size_t)row * NN + c] = s;
        lmax = fmaxf(lmax, s);
    }
#pragma unroll
    for (int o = 32; o > 0; o >>= 1) lmax = fmaxf(lmax, __shfl_down(lmax, o, 64));
    if ((tid & 63) == 0) red[tid >> 6] = lmax;
    __syncthreads();
    const float rmax = fmaxf(fmaxf(red[0], red[1]), fmaxf(red[2], red[3]));
    __syncthreads();

    float lsum = 0.f;
    for (int c = tid; c < NN; c += 256) {
        float v = expf(A[(size_t)row * NN + c] - rmax);
        A[(size_t)row * NN + c] = v;
        lsum += v;
    }
#pragma unroll
    for (int o = 32; o > 0; o >>= 1) lsum += __shfl_down(lsum, o, 64);
    if ((tid & 63) == 0) red[4 + (tid >> 6)] = lsum;
    __syncthreads();
    const float inv = 1.f / (red[4] + red[5] + red[6] + red[7]);
    for (int c = tid; c < NN; c += 256) A[(size_t)row * NN + c] *= inv;
}

// ---------------- A_f32 -> A_bf [2048][2048] with zero pad ----------------
__global__ __launch_bounds__(256) void convert_A(const float* __restrict__ Af,
                                                 ushort_t* __restrict__ Ab) {
    size_t idx = (size_t)blockIdx.x * 256 + threadIdx.x;
    int r = (int)(idx >> 11), c = (int)(idx & 2047);
    float v = (r < NN && c < NN) ? Af[(size_t)r * NN + c] : 0.f;
    Ab[idx] = f2bf(v);
}

// ---------------- Ax[b,t,n] = sum_m A[n,m] x[b,t,m]  (f32, one-time) ----------------
// v7 = r16's v5 with As stride 66->67 only (fixes 4-way As-write conflicts; As reads
// are per-lane scalar, xs keeps stride 26 + float2 reads). Bit-identical Ax.
__global__ __launch_bounds__(256) void ax2_kernel(const float* __restrict__ A,
                                                  const float* __restrict__ x,
                                                  float* __restrict__ Ax) {
    __shared__ float As[64][67];  // [mm][r]
    __shared__ float xs[64][26];  // [mm][t], 24 used
    const int n0 = blockIdx.x * 64;
    const int b = blockIdx.y;
    const int tid = threadIdx.x;
    const int lane = tid & 63, cq = tid >> 6;  // cq = wave id, cols cq*6..cq*6+5
    float acc[6] = {};

    for (int m0 = 0; m0 < NN; m0 += 64) {
#pragma unroll
        for (int l = 0; l < 16; ++l) {
            int idx = tid + l * 256;
            int mm = idx & 63, r = idx >> 6;
            int n = n0 + r, m = m0 + mm;
            As[mm][r] = (n < NN && m < NN) ? A[(size_t)n * NN + m] : 0.f;
        }
#pragma unroll
        for (int l = 0; l < 6; ++l) {
            int idx = tid + l * 256;
            int mm = idx & 63, t = idx >> 6;
            int m = m0 + mm;
            xs[mm][t] = (m < NN) ? x[((size_t)b * TT + t) * NN + m] : 0.f;
        }
        __syncthreads();
#pragma unroll 4
        for (int mm = 0; mm < 64; ++mm) {
            const float a = As[mm][lane];
            float2 x01 = *(const float2*)&xs[mm][cq * 6];
            float2 x23 = *(const float2*)&xs[mm][cq * 6 + 2];
            float2 x45 = *(const float2*)&xs[mm][cq * 6 + 4];
            acc[0] += a * x01.x;
            acc[1] += a * x01.y;
            acc[2] += a * x23.x;
            acc[3] += a * x23.y;
            acc[4] += a * x45.x;
            acc[5] += a * x45.y;
        }
        __syncthreads();
    }
    const int n = n0 + lane;
    if (n < NN) {
#pragma unroll
        for (int j = 0; j < 6; ++j) {
            const int t = cq * 6 + j;
            Ax[((size_t)b * TT + t) * NN + n] = acc[j];
        }
    }
}

// ================== device bodies ==================

// MFMA GEMM body: 128x128 tile, BK=64, 32 KB smem. NW = waves/block (4 or 8).
template <int NW>
__device__ __forceinline__ void gemm_body(int bx, int by,
                                          const ushort_t* __restrict__ Ab,
                                          const ushort_t* __restrict__ H,
                                          ushort_t* __restrict__ Y, char* smem) {
    constexpr int TH = NW * 64;
    constexpr int SPW = 8 / NW;  // j-subtiles per wave
    ushort_t* As = (ushort_t*)smem;             // 16 KB (128 rows x 64 k)
    ushort_t* Bs = (ushort_t*)(smem + 16384);   // 16 KB (two 8 KB halves)
    const int tid = threadIdx.x;
    const int w = tid >> 6, l = tid & 63, lr = l & 15, lg = l >> 4;
    const int n0 = bx * 128, j0 = by * 128;
    f32x4 acc[8][SPW] = {};

    const unsigned bs0 = lds_off(Bs);
    unsigned btr_b[SPW];
#pragma unroll
    for (int nt = 0; nt < SPW; ++nt)
        btr_b[nt] = bs0 + 2u * ((unsigned)(w * SPW + nt) * 512 + (unsigned)lg * 128 + (unsigned)lr);

    for (int ks = 0; ks < NP / 64; ++ks) {
        const int k0 = ks * 64;
#pragma unroll
        for (int p = 0; p < 1024 / TH; ++p) {  // A: 128x64, XOR-swizzled
            const int idx = p * TH + tid;
            const int row = idx >> 3, sl = idx & 7;
            glld16(Ab + (size_t)(n0 + row) * NP + k0 + ((sl ^ (row & 7)) << 3),
                   (ushort_t*)((char*)As + idx * 16));
        }
#pragma unroll
        for (int p = 0; p < 1024 / TH; ++p) {  // B: two 32-row halves, tr-read subtile order
            const int idx = p * TH + tid;
            const int g = idx >> 9, li = idx & 511;
            const int row = k0 + g * 32 + ((li >> 3) & 7) * 4 + ((li >> 1) & 3);
            const int col = j0 + (li >> 6) * 16 + (li & 1) * 8;
            glld16(H + (size_t)row * BC + col,
                   (ushort_t*)((char*)Bs + g * 8192 + li * 16));
        }
        __syncthreads();

        unsigned long long bq[2][SPW][2];  // [kk][nt][half]
        if constexpr (SPW == 2) {
            asm volatile(
                "ds_read_b64_tr_b16 %0, %8 offset:0\n\t"
                "ds_read_b64_tr_b16 %1, %8 offset:128\n\t"
                "ds_read_b64_tr_b16 %2, %9 offset:0\n\t"
                "ds_read_b64_tr_b16 %3, %9 offset:128\n\t"
                "ds_read_b64_tr_b16 %4, %8 offset:8192\n\t"
                "ds_read_b64_tr_b16 %5, %8 offset:8320\n\t"
                "ds_read_b64_tr_b16 %6, %9 offset:8192\n\t"
                "ds_read_b64_tr_b16 %7, %9 offset:8320"
                : "=v"(bq[0][0][0]), "=v"(bq[0][0][1]), "=v"(bq[0][1][0]), "=v"(bq[0][1][1]),
                  "=v"(bq[1][0][0]), "=v"(bq[1][0][1]), "=v"(bq[1][1][0]), "=v"(bq[1][1][1])
                : "v"(btr_b[0]), "v"(btr_b[1]));
        } else {
            asm volatile(
                "ds_read_b64_tr_b16 %0, %4 offset:0\n\t"
                "ds_read_b64_tr_b16 %1, %4 offset:128\n\t"
                "ds_read_b64_tr_b16 %2, %4 offset:8192\n\t"
                "ds_read_b64_tr_b16 %3, %4 offset:8320"
                : "=v"(bq[0][0][0]), "=v"(bq[0][0][1]), "=v"(bq[1][0][0]), "=v"(bq[1][0][1])
                : "v"(btr_b[0]));
        }
        asm volatile("s_waitcnt lgkmcnt(0)" ::: "memory");
        __builtin_amdgcn_sched_barrier(0);
        bf16x8 bv[2][SPW];
#pragma unroll
        for (int kk = 0; kk < 2; ++kk)
#pragma unroll
            for (int nt = 0; nt < SPW; ++nt) {
                union { unsigned long long q[2]; bf16x8 f; } u;
                u.q[0] = bq[kk][nt][0];
                u.q[1] = bq[kk][nt][1];
                bv[kk][nt] = u.f;
            }

#pragma unroll
        for (int kk = 0; kk < 2; ++kk)
#pragma unroll
            for (int m = 0; m < 8; ++m) {
                const int rr = m * 16 + lr;
                const bf16x8 av = *(const bf16x8*)&As[rr * 64 + (((kk * 4 + lg) ^ (rr & 7)) << 3)];
#pragma unroll
                for (int nt = 0; nt < SPW; ++nt)
                    acc[m][nt] = __builtin_amdgcn_mfma_f32_16x16x32_bf16(av, bv[kk][nt], acc[m][nt], 0, 0, 0);
            }
        __syncthreads();
    }

#pragma unroll
    for (int m = 0; m < 8; ++m)
#pragma unroll
        for (int r = 0; r < 4; ++r) {
            const int n = n0 + m * 16 + lg * 4 + r;
            if (n < NN) {
#pragma unroll
                for (int nt = 0; nt < SPW; ++nt)
                    Y[(size_t)n * BC + j0 + (w * SPW + nt) * 16 + lr] = f2bf(acc[m][nt][r]);
            }
        }
}

// factored-MFMA NAPL body (LDS-staged + av-hoist over d). smem = NSEGS*8 KB. 4 waves.
template <int NSEGS, int CO, bool GATE, bool HASX>
__device__ __forceinline__ void napl_body(
    int bid, char* smem,
    const ushort_t* __restrict__ Bt, const float* __restrict__ bp,
    const float* __restrict__ emb, const float* __restrict__ WxPool,
    const ushort_t* __restrict__ s0p, const ushort_t* __restrict__ s1p,
    const ushort_t* __restrict__ s2p, const ushort_t* __restrict__ s3p,
    const float* __restrict__ xv, const float* __restrict__ axv,
    const float* hf, float* __restrict__ zf,
    ushort_t* __restrict__ outb, float* outf, int t) {
    constexpr int K = NSEGS * 64;
    constexpr int NT = (CO == 128) ? 2 : 1;
    constexpr int NHALF = NSEGS / 2;
    ushort_t* As = (ushort_t*)smem;
    const int tid = threadIdx.x;
    const int w = tid >> 6, l = tid & 63, lr = l & 15, lg = l >> 4;
    const int n0 = bid * 2;
    const int ob = w * (16 * NT);
    const ushort_t* segs[4] = {s0p, s1p, s2p, s3p};

#pragma unroll
    for (int s = 0; s < NSEGS; ++s) {
        const ushort_t* sp = segs[s];
#pragma unroll
        for (int p = 0; p < 2; ++p) {
            const int idx = p * 256 + tid;
            const int row = idx >> 3, c16 = idx & 7;
            glld16(sp + (size_t)(n0 + (row >> 5)) * BC + (row & 31) * 64 +
                       ((c16 ^ (row & 7)) << 3),
                   (ushort_t*)((char*)As + s * 8192 + idx * 16));
        }
    }
    __syncthreads();

    f32x4 OUT[4][NT] = {};
#pragma unroll 1
    for (int hf2 = 0; hf2 < NHALF; ++hf2) {
        bf16x8 av[4][4];  // [c][m], c = s_local*2 + h2
#pragma unroll
        for (int c = 0; c < 4; ++c) {
            const int s = hf2 * 2 + (c >> 1);
            const int kin = (c & 1) * 32 + lg * 8;
#pragma unroll
            for (int m = 0; m < 4; ++m) {
                const int rr = m * 16 + lr;
                av[c][m] = *(const bf16x8*)&As[s * 4096 + rr * 64 + (kin ^ ((rr & 7) << 3))];
            }
        }
#pragma unroll 1
        for (int d = 0; d < DD; ++d) {
            const ushort_t* btd = Bt + (size_t)d * CO * K;
            const float ea = emb[n0 * DD + d];
            const float eb = emb[(n0 + 1) * DD + d];
            f32x4 P[4][NT] = {};
#pragma unroll
            for (int c = 0; c < 4; ++c) {
                const int kg = (hf2 * 2 + (c >> 1)) * 64 + (c & 1) * 32 + lg * 8;
                bf16x8 bv[NT];
#pragma unroll
                for (int nt = 0; nt < NT; ++nt)
                    bv[nt] = *(const bf16x8*)&btd[(size_t)(ob + nt * 16 + lr) * K + kg];
#pragma unroll
                for (int m = 0; m < 4; ++m)
#pragma unroll
                    for (int nt = 0; nt < NT; ++nt)
                        P[m][nt] = __builtin_amdgcn_mfma_f32_16x16x32_bf16(av[c][m], bv[nt], P[m][nt], 0, 0, 0);
            }
#pragma unroll
            for (int m = 0; m < 4; ++m) {
                const float e = (m < 2) ? ea : eb;
#pragma unroll
                for (int nt = 0; nt < NT; ++nt)
#pragma unroll
                    for (int r = 0; r < 4; ++r)
                        OUT[m][nt][r] += e * P[m][nt][r];
            }
        }
    }

    float bias[2][NT];
#pragma unroll
    for (int nd = 0; nd < 2; ++nd)
#pragma unroll
        for (int nt = 0; nt < NT; ++nt) {
            float s_ = 0.f;
#pragma unroll
            for (int d = 0; d < DD; ++d)
                s_ += emb[(n0 + nd) * DD + d] * bp[d * CO + ob + nt * 16 + lr];
            bias[nd][nt] = s_;
        }
    float wx[2][2][NT] = {};
    if (HASX) {
#pragma unroll
        for (int kk = 0; kk < 2; ++kk)
#pragma unroll
            for (int nd = 0; nd < 2; ++nd)
#pragma unroll
                for (int nt = 0; nt < NT; ++nt) {
                    float s_ = 0.f;
#pragma unroll
                    for (int d = 0; d < DD; ++d)
                        s_ += emb[(n0 + nd) * DD + d] *
                              WxPool[(size_t)(d * 2 + kk) * 65 * CO + ob + nt * 16 + lr];
                    wx[kk][nd][nt] = s_;
                }
    }

#pragma unroll
    for (int m = 0; m < 4; ++m) {
        const int nd = m >> 1;
        const int n = n0 + nd;
#pragma unroll
        for (int r = 0; r < 4; ++r) {
            const int row = m * 16 + lg * 4 + r;
            const int b = row & 31;
            const size_t nb = (size_t)n * BC + b * 64;
            float xt = 0.f, axt = 0.f;
            if (HASX) {
                xt = xv[((size_t)b * TT + t) * NN + n];
                axt = axv[((size_t)b * TT + t) * NN + n];
            }
#pragma unroll
            for (int nt = 0; nt < NT; ++nt) {
                const int o = ob + nt * 16 + lr;
                float val = OUT[m][nt][r] + bias[nd][nt];
                if (HASX) val += xt * wx[0][nd][nt] + axt * wx[1][nd][nt];
                if (GATE) {
                    const float sg = sigmoidf_(val);
                    if (ob < 64) {
                        zf[nb + o] = sg;
                    } else {
                        outb[nb + (o - 64)] = f2bf(sg * hf[nb + (o - 64)]);
                    }
                } else {
                    const float hc = tanhf(val);
                    const float z = zf[nb + o];
                    const float hn = z * hf[nb + o] + (1.f - z) * hc;
                    outf[nb + o] = hn;
                    outb[nb + o] = f2bf(hn);
                }
            }
        }
    }
}

// ================== kernels ==================

__global__ __launch_bounds__(512) void gemm_trb(const ushort_t* __restrict__ Ab,
                                                const ushort_t* __restrict__ H0,
                                                ushort_t* __restrict__ Y0,
                                                const ushort_t* __restrict__ H1,
                                                ushort_t* __restrict__ Y1) {
    __shared__ __align__(16) char smem[32768];
    gemm_body<8>(blockIdx.x, blockIdx.y, Ab,
                 (blockIdx.z == 0) ? H0 : H1, (blockIdx.z == 0) ? Y0 : Y1, smem);
}

template <int NSEGS, int CO, bool GATE, bool HASX>
__global__ __launch_bounds__(256) void napl2(
    const ushort_t* __restrict__ Bt, const float* __restrict__ bp,
    const float* __restrict__ emb, const float* __restrict__ WxPool,
    const ushort_t* __restrict__ s0p, const ushort_t* __restrict__ s1p,
    const ushort_t* __restrict__ s2p, const ushort_t* __restrict__ s3p,
    const float* __restrict__ xv, const float* __restrict__ axv,
    const float* hf, float* __restrict__ zf,
    ushort_t* __restrict__ outb, float* outf, int t) {
    __shared__ __align__(16) char smem[NSEGS * 8192];
    napl_body<NSEGS, CO, GATE, HASX>(blockIdx.x, smem, Bt, bp, emb, WxPool,
                                     s0p, s1p, s2p, s3p, xv, axv, hf, zf, outb, outf, t);
}

// ---- r13-path merged kernels (4-wave gemm body; fallback only) ----
__global__ __launch_bounds__(256) void mergeA_k(
    const ushort_t* __restrict__ Abf, const ushort_t* __restrict__ Hg,
    ushort_t* __restrict__ Yg,
    const ushort_t* __restrict__ Bt, const float* __restrict__ bp,
    const float* __restrict__ emb, const float* __restrict__ Wx,
    const ushort_t* __restrict__ s0, const ushort_t* __restrict__ s1,
    const float* __restrict__ xv, const float* __restrict__ axv,
    const float* hf, float* __restrict__ zf, ushort_t* __restrict__ outb, int t) {
    __shared__ __align__(16) char smem[32768];
    const int g = blockIdx.x;
    if (g < 256)
        gemm_body<4>(g & 15, g >> 4, Abf, Hg, Yg, smem);
    else
        napl_body<2, 128, true, true>(g - 256, smem, Bt, bp, emb, Wx,
                                      s0, s1, s0, s0, xv, axv, hf, zf, outb, nullptr, t);
}

__global__ __launch_bounds__(256) void mergeB_k(
    const ushort_t* __restrict__ Abf, const ushort_t* __restrict__ Hg,
    ushort_t* __restrict__ Yg,
    const ushort_t* __restrict__ Bt, const float* __restrict__ bp,
    const float* __restrict__ emb,
    const ushort_t* __restrict__ s0, const ushort_t* __restrict__ s1,
    const ushort_t* __restrict__ s2, const ushort_t* __restrict__ s3,
    const float* hf, float* __restrict__ zf,
    ushort_t* __restrict__ outb, float* outf, int t) {
    __shared__ __align__(16) char smem[32768];
    const int g = blockIdx.x;
    if (g < 256)
        gemm_body<4>(g & 15, g >> 4, Abf, Hg, Yg, smem);
    else
        napl_body<4, 64, false, false>(g - 256, smem, Bt, bp, emb, nullptr,
                                       s0, s1, s2, s3, nullptr, nullptr, hf, zf, outb, outf, t);
}

__global__ __launch_bounds__(256) void mergeC_k(
    const ushort_t* __restrict__ Abf, const ushort_t* __restrict__ Hg,
    ushort_t* __restrict__ Yg,
    const ushort_t* __restrict__ Bt, const float* __restrict__ bp,
    const float* __restrict__ emb, const float* __restrict__ Wx,
    const ushort_t* __restrict__ s0, const ushort_t* __restrict__ s1,
    const float* __restrict__ xv, const float* __restrict__ axv,
    const float* hf, float* __restrict__ zf,
    ushort_t* __restrict__ outb, float* outf, int t) {
    __shared__ __align__(16) char smem[32768];
    const int g = blockIdx.x;
    if (g < 256)
        gemm_body<4>(g & 15, g >> 4, Abf, Hg, Yg, smem);
    else
        napl_body<2, 64, false, true>(g - 256, smem, Bt, bp, emb, Wx,
                                      s0, s1, s0, s0, xv, axv, hf, zf, outb, outf, t);
}

// ---- pipe2 merged kernels ----
// mergeG: blocks [0,1000) = layer1 GATE (t); [1000,2000) = layer0 GATE (t+1)
__global__ __launch_bounds__(256) void mergeG_k(
    const ushort_t* __restrict__ Btg1, const float* __restrict__ bg1,
    const ushort_t* __restrict__ Btg0, const float* __restrict__ bg0,
    const float* __restrict__ emb, const float* __restrict__ Wg0,
    const ushort_t* __restrict__ hbt, const ushort_t* __restrict__ Ah0,
    const ushort_t* __restrict__ h1b, const ushort_t* __restrict__ AhX,
    const float* __restrict__ xv, const float* __restrict__ axv,
    const float* h0f, const float* h1f,
    float* __restrict__ zf0, float* __restrict__ zf1,
    ushort_t* __restrict__ rhb0, ushort_t* __restrict__ rhb1, int t) {
    __shared__ __align__(16) char smem[32768];
    const int g = blockIdx.x;
    if (g < 1000)
        napl_body<4, 128, true, false>(g, smem, Btg1, bg1, emb, nullptr,
                                       hbt, Ah0, h1b, AhX, nullptr, nullptr,
                                       h1f, zf1, rhb1, nullptr, t);
    else
        napl_body<2, 128, true, true>(g - 1000, smem, Btg0, bg0, emb, Wg0,
                                      hbt, Ah0, hbt, hbt, xv, axv,
                                      h0f, zf0, rhb0, nullptr, t + 1);
}

// mergeCC: blocks [0,1000) = layer1 CAND (t); [1000,2000) = layer0 CAND (t+1)
__global__ __launch_bounds__(256) void mergeCC_k(
    const ushort_t* __restrict__ Btc1, const float* __restrict__ bc1,
    const ushort_t* __restrict__ Btc0, const float* __restrict__ bc0,
    const float* __restrict__ emb, const float* __restrict__ Wc0,
    const ushort_t* __restrict__ hbt, ushort_t* __restrict__ hbt1,
    const ushort_t* __restrict__ Ah0, const ushort_t* __restrict__ rhb1,
    const ushort_t* __restrict__ AhX, const ushort_t* __restrict__ AhY,
    const ushort_t* __restrict__ rhb0,
    const float* __restrict__ xv, const float* __restrict__ axv,
    float* h0f, float* h1f,
    float* __restrict__ zf0, float* __restrict__ zf1,
    ushort_t* __restrict__ h1b, int t) {
    __shared__ __align__(16) char smem[32768];
    const int g = blockIdx.x;
    if (g < 1000)
        napl_body<4, 64, false, false>(g, smem, Btc1, bc1, emb, nullptr,
                                       hbt, Ah0, rhb1, AhX, nullptr, nullptr,
                                       h1f, zf1, h1b, h1f, t);
    else
        napl_body<2, 64, false, true>(g - 1000, smem, Btc0, bc0, emb, Wc0,
                                      rhb0, AhY, rhb0, rhb0, xv, axv,
                                      h0f, zf0, hbt1, h0f, t + 1);
}

// ---------------- prep: Bt[d][o][K] bf16 from pool (B^T form for MFMA) ----------------
template <int CI, int CO, bool L0>
__global__ __launch_bounds__(256) void prepW(const float* __restrict__ Wp,
                                             ushort_t* __restrict__ Bt) {
    constexpr int K = L0 ? 128 : 256;
    const int idx = blockIdx.x * 256 + threadIdx.x;
    if (idx >= DD * CO * K) return;
    const int d = idx / (CO * K);
    const int rem = idx - d * CO * K;
    const int o = rem / K;
    const int k = rem - o * K;
    const int s = k >> 6, c = k & 63;
    const int kk = L0 ? s : (s & 1);
    const int i = L0 ? (1 + c) : ((s >> 1) * 64 + c);
    Bt[idx] = f2bf(Wp[((size_t)(d * 2 + kk) * CI + i) * CO + o]);
}

// ---------------- head ----------------
__global__ __launch_bounds__(256) void head_kernel(const float* __restrict__ h1,
                                                   const float* __restrict__ hw,
                                                   const float* __restrict__ hb,
                                                   float* __restrict__ y) {
    __shared__ float wl[T_OUT * HH];
    const int tid = threadIdx.x;
    for (int idx = tid; idx < T_OUT * HH; idx += 256) wl[idx] = hw[idx];
    __syncthreads();
    const int gi = blockIdx.x * 256 + tid;
    if (gi >= BB * NN) return;
    const int b = gi / NN, n = gi % NN;
    float acc[T_OUT];
#pragma unroll
    for (int ot = 0; ot < T_OUT; ++ot) acc[ot] = hb[ot];
    for (int h = 0; h < HH; ++h) {
        float v = h1[(size_t)n * BC + b * 64 + h];
#pragma unroll
        for (int ot = 0; ot < T_OUT; ++ot) acc[ot] += v * wl[ot * HH + h];
    }
#pragma unroll
    for (int ot = 0; ot < T_OUT; ++ot)
        y[((size_t)b * T_OUT + ot) * NN + n] = acc[ot];
}

extern "C" void kernel_launch(void* const* d_in, const int* in_sizes, int n_in,
                              void* d_out, int out_size, void* d_ws, size_t ws_size,
                              hipStream_t stream) {
    const float* x = (const float*)d_in[0];
    const float* node_emb = (const float*)d_in[1];
    const float* adapt_emb = (const float*)d_in[2];
    const float* Wg0 = (const float*)d_in[3];
    const float* bg0 = (const float*)d_in[4];
    const float* Wc0 = (const float*)d_in[5];
    const float* bc0 = (const float*)d_in[6];
    const float* Wg1 = (const float*)d_in[7];
    const float* bg1 = (const float*)d_in[8];
    const float* Wc1 = (const float*)d_in[9];
    const float* bc1 = (const float*)d_in[10];
    const float* head_w = (const float*)d_in[11];
    const float* head_b = (const float*)d_in[12];
    float* y = (float*)d_out;

    char* ws = (char*)d_ws;
    ushort_t* Abf  = (ushort_t*)(ws + ABF_OFF);
    float* h0f = (float*)(ws + H0F_OFF);
    float* h1f = (float*)(ws + H1F_OFF);
    float* zf  = (float*)(ws + ZF_OFF);
    ushort_t* h0b = (ushort_t*)(ws + H0B_OFF);
    ushort_t* h1b = (ushort_t*)(ws + H1B_OFF);
    ushort_t* rhb = (ushort_t*)(ws + RHB_OFF);
    ushort_t* Ah0 = (ushort_t*)(ws + AH0_OFF);
    ushort_t* AhX = (ushort_t*)(ws + AHX_OFF);
    float* Axf = (float*)(ws + AXF_OFF);
    ushort_t* Btg0 = (ushort_t*)(ws + BTG0_OFF);
    ushort_t* Btc0 = (ushort_t*)(ws + BTC0_OFF);
    ushort_t* Btg1 = (ushort_t*)(ws + BTG1_OFF);
    ushort_t* Btc1 = (ushort_t*)(ws + BTC1_OFF);
    float* Af32 = zf;  // overlay: consumed before first gate writes z

    const bool pipe2 = (ws_size >= TOP_PIPE2);
    const bool pipe = (ws_size >= TOP_PIPE);

    hipMemsetAsync(h0f, 0, SZ_ST4, stream);
    hipMemsetAsync(h1f, 0, SZ_ST4, stream);
    hipMemsetAsync(h0b, 0, SZ_NPB2, stream);
    hipMemsetAsync(h1b, 0, SZ_NPB2, stream);
    hipMemsetAsync(rhb, 0, SZ_NPB2, stream);
    hipMemsetAsync(Ah0, 0, SZ_NPB2, stream);
    hipMemsetAsync(AhX, 0, SZ_NPB2, stream);

    compute_A_kernel<<<NN, 256, 0, stream>>>(adapt_emb, Af32);
    ax2_kernel<<<dim3(32, 32), 256, 0, stream>>>(Af32, x, Axf);
    convert_A<<<(NP * NP) / 256, 256, 0, stream>>>(Af32, Abf);
    prepW<65, 128, true><<<(DD * 128 * 128 + 255) / 256, 256, 0, stream>>>(Wg0, Btg0);
    prepW<65, 64, true><<<(DD * 64 * 128 + 255) / 256, 256, 0, stream>>>(Wc0, Btc0);
    prepW<128, 128, false><<<(DD * 128 * 256 + 255) / 256, 256, 0, stream>>>(Wg1, Btg1);
    prepW<128, 64, false><<<(DD * 64 * 256 + 255) / 256, 256, 0, stream>>>(Wc1, Btc1);

    const dim3 gG1(NP / 128, NP / 128, 1);  // 256 blocks
    const dim3 gG2(NP / 128, NP / 128, 2);  // dual GEMM: 512 blocks
    const int gN = NN * BB / 64;            // 1000 blocks

    if (pipe2) {
        float* zf0 = zf;
        ushort_t* rhb0 = rhb;
        float* zf1 = (float*)(ws + ZF1_OFF);
        ushort_t* rhb1 = (ushort_t*)(ws + RHB1_OFF);
        ushort_t* AhY = (ushort_t*)(ws + AHY_OFF);
        ushort_t* h0b2 = (ushort_t*)(ws + H0B2_OFF);
        hipMemsetAsync(rhb1, 0, SZ_NPB2, stream);
        hipMemsetAsync(h0b2, 0, SZ_NPB2, stream);
        ushort_t* hb[2] = {h0b, h0b2};  // C0(t) writes hb[t&1]

        // prologue: G0(0), R0(0), C0(0) -> hb[0], G2(0) -> Ah0
        napl2<2, 128, true, true><<<gN, 256, 0, stream>>>(
            Btg0, bg0, node_emb, Wg0, h0b, Ah0, h0b, h0b, x, Axf, h0f, zf0, rhb0, nullptr, 0);
        gemm_trb<<<gG1, 512, 0, stream>>>(Abf, rhb0, AhY, rhb0, AhY);
        napl2<2, 64, false, true><<<gN, 256, 0, stream>>>(
            Btc0, bc0, node_emb, Wc0, rhb0, AhY, rhb0, rhb0, x, Axf, h0f, zf0, hb[0], h0f, 0);
        gemm_trb<<<gG1, 512, 0, stream>>>(Abf, hb[0], Ah0, hb[0], Ah0);

        for (int t = 0; t < TT - 1; ++t) {
            ushort_t* hbt = hb[t & 1];
            ushort_t* hbt1 = hb[(t + 1) & 1];
            // D1: G1(t) || G0(t+1)
            mergeG_k<<<2000, 256, 0, stream>>>(Btg1, bg1, Btg0, bg0, node_emb, Wg0,
                hbt, Ah0, h1b, AhX, x, Axf, h0f, h1f, zf0, zf1, rhb0, rhb1, t);
            // D2: R1(t): AhX <- A@rhb1 || R0(t+1): AhY <- A@rhb0
            gemm_trb<<<gG2, 512, 0, stream>>>(Abf, rhb1, AhX, rhb0, AhY);
            // D3: C1(t) -> h1f,h1b || C0(t+1) -> h0f,hbt1
            mergeCC_k<<<2000, 256, 0, stream>>>(Btc1, bc1, Btc0, bc0, node_emb, Wc0,
                hbt, hbt1, Ah0, rhb1, AhX, AhY, rhb0, x, Axf, h0f, h1f, zf0, zf1, h1b, t);
            // D4: AhX <- A@h1b || Ah0 <- A@hbt1
            gemm_trb<<<gG2, 512, 0, stream>>>(Abf, h1b, AhX, hbt1, Ah0);
        }
        // epilogue t=TT-1
        {
            ushort_t* hbT = hb[(TT - 1) & 1];
            napl2<4, 128, true, false><<<gN, 256, 0, stream>>>(
                Btg1, bg1, node_emb, nullptr, hbT, Ah0, h1b, AhX, nullptr, nullptr, h1f, zf1, rhb1, nullptr, TT - 1);
            gemm_trb<<<gG1, 512, 0, stream>>>(Abf, rhb1, AhX, rhb1, AhX);
            napl2<4, 64, false, false><<<gN, 256, 0, stream>>>(
                Btc1, bc1, node_emb, nullptr, hbT, Ah0, rhb1, AhX, nullptr, nullptr, h1f, zf1, h1b, h1f, TT - 1);
        }
    } else if (pipe) {
        float* zf0 = zf;
        ushort_t* rhb0 = rhb;
        float* zf1 = (float*)(ws + ZF1_OFF);
        ushort_t* rhb1 = (ushort_t*)(ws + RHB1_OFF);
        ushort_t* AhY = (ushort_t*)(ws + AHY_OFF);
        hipMemsetAsync(rhb1, 0, SZ_NPB2, stream);

        napl2<2, 128, true, true><<<gN, 256, 0, stream>>>(
            Btg0, bg0, node_emb, Wg0, h0b, Ah0, h0b, h0b, x, Axf, h0f, zf0, rhb0, nullptr, 0);
        gemm_trb<<<gG1, 512, 0, stream>>>(Abf, rhb0, AhY, rhb0, AhY);
        napl2<2, 64, false, true><<<gN, 256, 0, stream>>>(
            Btc0, bc0, node_emb, Wc0, rhb0, AhY, rhb0, rhb0, x, Axf, h0f, zf0, h0b, h0f, 0);
        gemm_trb<<<gG2, 512, 0, stream>>>(Abf, h0b, Ah0, h1b, AhX);
        napl2<4, 128, true, false><<<gN, 256, 0, stream>>>(
            Btg1, bg1, node_emb, nullptr, h0b, Ah0, h1b, AhX, nullptr, nullptr, h1f, zf1, rhb1, nullptr, 0);

        for (int t = 0; t < TT - 1; ++t) {
            mergeA_k<<<1256, 256, 0, stream>>>(Abf, rhb1, AhX,
                Btg0, bg0, node_emb, Wg0, h0b, Ah0, x, Axf, h0f, zf0, rhb0, t + 1);
            mergeB_k<<<1256, 256, 0, stream>>>(Abf, rhb0, AhY,
                Btc1, bc1, node_emb, h0b, Ah0, rhb1, AhX, h1f, zf1, h1b, h1f, t);
            mergeC_k<<<1256, 256, 0, stream>>>(Abf, h1b, AhX,
                Btc0, bc0, node_emb, Wc0, rhb0, AhY, x, Axf, h0f, zf0, h0b, h0f, t + 1);
            gemm_trb<<<gG1, 512, 0, stream>>>(Abf, h0b, Ah0, h0b, Ah0);
            napl2<4, 128, true, false><<<gN, 256, 0, stream>>>(
                Btg1, bg1, node_emb, nullptr, h0b, Ah0, h1b, AhX, nullptr, nullptr, h1f, zf1, rhb1, nullptr, t + 1);
        }
        gemm_trb<<<gG1, 512, 0, stream>>>(Abf, rhb1, AhX, rhb1, AhX);
        napl2<4, 64, false, false><<<gN, 256, 0, stream>>>(
            Btc1, bc1, node_emb, nullptr, h0b, Ah0, rhb1, AhX, nullptr, nullptr, h1f, zf1, h1b, h1f, TT - 1);
    } else {
        for (int t = 0; t < TT; ++t) {
            napl2<2, 128, true, true><<<gN, 256, 0, stream>>>(
                Btg0, bg0, node_emb, Wg0, h0b, Ah0, h0b, h0b, x, Axf, h0f, zf, rhb, nullptr, t);
            gemm_trb<<<gG1, 512, 0, stream>>>(Abf, rhb, AhX, rhb, AhX);
            napl2<2, 64, false, true><<<gN, 256, 0, stream>>>(
                Btc0, bc0, node_emb, Wc0, rhb, AhX, rhb, rhb, x, Axf, h0f, zf, h0b, h0f, t);
            gemm_trb<<<gG2, 512, 0, stream>>>(Abf, h0b, Ah0, h1b, AhX);
            napl2<4, 128, true, false><<<gN, 256, 0, stream>>>(
                Btg1, bg1, node_emb, nullptr, h0b, Ah0, h1b, AhX, nullptr, nullptr, h1f, zf, rhb, nullptr, t);
            gemm_trb<<<gG1, 512, 0, stream>>>(Abf, rhb, AhX, rhb, AhX);
            napl2<4, 64, false, false><<<gN, 256, 0, stream>>>(
                Btc1, bc1, node_emb, nullptr, h0b, Ah0, rhb, AhX, nullptr, nullptr, h1f, zf, h1b, h1f, t);
        }
    }

    head_kernel<<<(BB * NN + 255) / 256, 256, 0, stream>>>(h1f, head_w, head_b, y);
}